// Round 14
// baseline (217.699 us; speedup 1.0000x reference)
//
#include <hip/hip_runtime.h>
#include <hip/hip_bf16.h>
#include <math.h>

#define XD 100
#define HD 64
#define TL 15
#define NHEADS 4
#define OUTD 32
#define TPB 8        // trees per treelstm block
#define PASS 4       // trees per LDS pass
#define NREP 32      // colsum replicas (atomic contention fix)
#define NB_SETUP 161
#define NB_COUNT 640
#define NB_FILL 640

typedef unsigned short ushort_t;
typedef unsigned int uint_t;
typedef __attribute__((ext_vector_type(8))) short bf16x8;
typedef __attribute__((ext_vector_type(4))) float f32x4;
typedef __attribute__((ext_vector_type(4))) unsigned short us4;

__device__ __forceinline__ ushort_t f2bf(float x) {
    __hip_bfloat16 h = __float2bfloat16(x);
    return *reinterpret_cast<ushort_t*>(&h);
}
__device__ __forceinline__ ushort_t f2bf_fast(float x) { // 3-op RNE (finite inputs)
    uint_t b = __float_as_uint(x);
    return (ushort_t)((b + 0x7FFFu + ((b >> 16) & 1u)) >> 16);
}
__device__ __forceinline__ float bf2f(ushort_t u) {
    unsigned int v = ((unsigned int)u) << 16;
    return __uint_as_float(v);
}
__device__ __forceinline__ float fsig(float x) {
    return __builtin_amdgcn_rcpf(1.0f + __expf(-x));
}
__device__ __forceinline__ float ftanh(float x) {
    return 2.0f * __builtin_amdgcn_rcpf(1.0f + __expf(-2.0f * x)) - 1.0f;
}
__device__ __forceinline__ void wave_barrier() {   // LDS handoff only, no vmcnt drain
    asm volatile("s_waitcnt lgkmcnt(0)" ::: "memory");
    __builtin_amdgcn_s_barrier();
}

// ---------------- K1: setup (blocks 0..160) || edge count (blocks 161..) ----------------
__global__ __launch_bounds__(256) void setup_count(
    const float* __restrict__ W_iou, const float* __restrict__ U_f_W,
    const float* __restrict__ U_iou, const float* __restrict__ Wt,
    const float* __restrict__ Wfc, const float* __restrict__ attn_l,
    const float* __restrict__ attn_r, const float* __restrict__ W_out,
    ushort_t* __restrict__ Wb_iou, ushort_t* __restrict__ Wb_f,
    ushort_t* __restrict__ Wb_u, float* __restrict__ B_lr,
    float* __restrict__ W_out_T, float* __restrict__ colsum_rep,
    const int* __restrict__ edge_dst, int* __restrict__ cnt, int E)
{
    __shared__ float A_s[8][HD];
    const int blk = blockIdx.x;
    const int tid = threadIdx.x;
    if (blk < 160) {
        int idx = blk * 256 + tid;               // [0, 40960)
        if (idx < 24576) {                       // W_iou: 4kt x 12nt
            int j = idx & 7, l = (idx >> 3) & 63, f = idx >> 9;
            int kt = f / 12, nt = f % 12;
            int k = kt * 32 + ((l >> 4) * 8) + j;
            int nn = nt * 16 + (l & 15);
            float v = (k < XD) ? W_iou[nn * XD + k] : 0.f;
            Wb_iou[idx] = f2bf(v);
        } else if (idx < 24576 + 4096) {         // U_f_W: 2kt x 4nt
            int t = idx - 24576;
            int j = t & 7, l = (t >> 3) & 63, f = t >> 9;
            int kt = f >> 2, nt = f & 3;
            int k = kt * 32 + ((l >> 4) * 8) + j;
            int nn = nt * 16 + (l & 15);
            Wb_f[t] = f2bf(U_f_W[nn * HD + k]);
        } else {                                  // U_iou: 2kt x 12nt
            int t = idx - 24576 - 4096;
            int j = t & 7, l = (t >> 3) & 63, f = t >> 9;
            int kt = f / 12, nt = f % 12;
            int k = kt * 32 + ((l >> 4) * 8) + j;
            int g = nt * 16 + (l & 15);
            Wb_u[t] = f2bf(U_iou[g * HD + k]);
        }
    } else if (blk == 160) {
        for (int o = tid; o < 8 * HD; o += 256) {
            int q = o >> 6, c = o & 63;
            int h = q & 3;
            const float* attn = (q < 4) ? attn_l : attn_r;
            float s = 0.f;
            #pragma unroll 4
            for (int oo = 0; oo < OUTD; ++oo)
                s = fmaf(attn[h * OUTD + oo], Wfc[(h * OUTD + oo) * HD + c], s);
            A_s[q][c] = s;
        }
        // zero colsum replicas (consumed by agg, launched 2 kernels later)
        for (int i = tid; i < NREP * 128; i += 256) colsum_rep[i] = 0.f;
        __syncthreads();
        for (int o = tid; o < 8 * XD; o += 256) {
            int q = o / XD, x = o - q * XD;
            float s = 0.f;
            #pragma unroll 4
            for (int c = 0; c < HD; ++c)
                s = fmaf(A_s[q][c], Wt[c * XD + x], s);
            B_lr[o] = s;
        }
        for (int idx = tid; idx < HD * OUTD; idx += 256) {
            int c = idx >> 5, o = idx & 31;
            W_out_T[idx] = W_out[o * HD + c];
        }
    } else {
        const int cb = blk - NB_SETUP;
        const int stride = NB_COUNT * 256;
        const int4* d4 = (const int4*)edge_dst;
        const int E4 = E >> 2;
        for (int e = cb * 256 + tid; e < E4; e += stride) {
            int4 v = d4[e];
            atomicAdd(&cnt[v.x], 1); atomicAdd(&cnt[v.y], 1);
            atomicAdd(&cnt[v.z], 1); atomicAdd(&cnt[v.w], 1);
        }
        for (int e = (E & ~3) + cb * 256 + tid; e < E; e += stride)
            atomicAdd(&cnt[edge_dst[e]], 1);
    }
}

// ---------------- K2: scan ----------------
__global__ __launch_bounds__(1024) void scan_kernel(
    const int* __restrict__ cnt, int* __restrict__ offs, int* __restrict__ cursor, int N)
{
    __shared__ int part[1024];
    const int tid = threadIdx.x;
    const int per = (N + 1023) >> 10;
    int begin = tid * per;
    int end = begin + per; if (end > N) end = N;
    int s = 0;
    for (int i = begin; i < end && i < N; ++i) s += cnt[i];
    part[tid] = s;
    __syncthreads();
    for (int off = 1; off < 1024; off <<= 1) {
        int t = (tid >= off) ? part[tid - off] : 0;
        __syncthreads();
        part[tid] += t;
        __syncthreads();
    }
    int run = part[tid] - s;
    for (int i = begin; i < end && i < N; ++i) {
        offs[i] = run; cursor[i] = run; run += cnt[i];
    }
    if (tid == 1023) offs[N] = part[1023];
}

// ---------------- K3: mega = treelstm || fill || elr, STRIPED ----------------
__global__ __launch_bounds__(256) void mega_kernel(
    // fill
    const int* __restrict__ edge_src, const int* __restrict__ edge_dst,
    int* __restrict__ cursor, int* __restrict__ csr_src, int E,
    // treelstm
    const float* __restrict__ ast_x, const float* __restrict__ c_init,
    const ushort_t* __restrict__ Wb_iou, const ushort_t* __restrict__ Wb_f,
    const ushort_t* __restrict__ Wb_u, const float* __restrict__ b_iou,
    const float* __restrict__ U_f_b, ushort_t* __restrict__ h_rootb,
    int Ntrees, int NB_TREE, int NB_TOTAL,
    // elr
    const float* __restrict__ cfg_type, const float* __restrict__ B_lr,
    float* __restrict__ el, float* __restrict__ er, int N)
{
    __shared__ __align__(16) char smem[39808];
    const int tid = threadIdx.x;

    // Bresenham stripe: tree blocks interleaved with fill/elr so they co-run.
    const long long b = blockIdx.x;
    const int fb0 = (int)((b * NB_TREE) / NB_TOTAL);
    const int fb1 = (int)(((b + 1) * NB_TREE) / NB_TOTAL);
    const bool is_tree = (fb1 > fb0);
    const int tree_idx = fb0;
    const int other_idx = (int)(b - fb0);

    if (is_tree) {
        ushort_t (*xsb)[136] = (ushort_t(*)[136])smem;                    // 17408 B
        ushort_t (*hlb)[72]  = (ushort_t(*)[72])(smem + 17408);           //  9216 B
        ushort_t (*cib)[68]  = (ushort_t(*)[68])(smem + 26624);           //  8704 B
        ushort_t (*htb)[72]  = (ushort_t(*)[72])(smem + 35328);           //  2304 B
        float    (*credb)[68]= (float(*)[68])(smem + 37632);              //  2176 B

        const int lane = tid & 63;
        const int w = tid >> 6;
        const int arow = lane & 15;
        const int kgrp = lane >> 4;
        const int h = w * 16 + arow;
        const int base = tree_idx * TPB;

        const float bi = b_iou[h], bo = b_iou[64 + h], bu = b_iou[128 + h];
        const float fb = U_f_b[h];

        bf16x8 Bl[12];
        #pragma unroll
        for (int kt = 0; kt < 4; ++kt)
            #pragma unroll
            for (int j = 0; j < 3; ++j)
                Bl[kt * 3 + j] = *(const bf16x8*)(Wb_iou + (((size_t)kt * 12 + (w + 4 * j)) * 64 + lane) * 8);
        bf16x8 Bf[2];
        #pragma unroll
        for (int kt = 0; kt < 2; ++kt)
            Bf[kt] = *(const bf16x8*)(Wb_f + (((size_t)kt * 4 + w) * 64 + lane) * 8);

        const float4* xb4 = (const float4*)ast_x;
        const float4* cb4p = (const float4*)c_init;
        float4 xv[6], cv[4];

        auto issueX = [&](int pb) {
            #pragma unroll
            for (int k = 0; k < 6; ++k) {
                int i4 = tid + k * 256;
                int idx = i4 < 1500 ? i4 : 1499;
                int tt = pb * PASS + idx / 375, rem = idx % 375;
                int n = base + tt; if (n >= Ntrees) n = Ntrees - 1;
                xv[k] = xb4[(size_t)n * 400 + 25 + rem];
            }
        };
        auto issueC = [&](int pb) {
            #pragma unroll
            for (int k = 0; k < 4; ++k) {
                int i4 = tid + k * 256;
                int idx = i4 < 960 ? i4 : 959;
                int lt = idx / 240, rem = idx % 240;
                int n = base + pb * PASS + lt; if (n >= Ntrees) n = Ntrees - 1;
                cv[k] = cb4p[(size_t)n * 256 + 16 + rem];
            }
        };
        auto writeX = [&]() {
            #pragma unroll
            for (int k = 0; k < 6; ++k) {
                int i4 = tid + k * 256;
                if (i4 < 1500) {
                    int lt = i4 / 375, rem = i4 - lt * 375;
                    int row = rem / 25, c4 = rem - row * 25;
                    us4 p;
                    p[0] = f2bf_fast(xv[k].x); p[1] = f2bf_fast(xv[k].y);
                    p[2] = f2bf_fast(xv[k].z); p[3] = f2bf_fast(xv[k].w);
                    *(us4*)&xsb[lt * 16 + row][c4 * 4] = p;
                }
            }
        };
        auto writeC = [&]() {
            #pragma unroll
            for (int k = 0; k < 4; ++k) {
                int i4 = tid + k * 256;
                if (i4 < 960) {
                    int lt = i4 / 240, rem = i4 - lt * 240;
                    int row = rem / 16, c4 = rem - row * 16;
                    us4 p;
                    p[0] = f2bf_fast(cv[k].x); p[1] = f2bf_fast(cv[k].y);
                    p[2] = f2bf_fast(cv[k].z); p[3] = f2bf_fast(cv[k].w);
                    *(us4*)&cib[lt * 16 + row][c4 * 4] = p;
                }
            }
        };

        float cl[PASS][4];
        float hsum[PASS];

        auto leaf_pass = [&]() {
            #pragma unroll
            for (int lt = 0; lt < PASS; ++lt) {
                f32x4 a0 = {0,0,0,0}, a1 = {0,0,0,0}, a2 = {0,0,0,0};
                #pragma unroll
                for (int kt = 0; kt < 4; ++kt) {
                    bf16x8 a = *(const bf16x8*)&xsb[lt * 16 + arow][kt * 32 + kgrp * 8];
                    a0 = __builtin_amdgcn_mfma_f32_16x16x32_bf16(a, Bl[kt * 3 + 0], a0, 0, 0, 0);
                    a1 = __builtin_amdgcn_mfma_f32_16x16x32_bf16(a, Bl[kt * 3 + 1], a1, 0, 0, 0);
                    a2 = __builtin_amdgcn_mfma_f32_16x16x32_bf16(a, Bl[kt * 3 + 2], a2, 0, 0, 0);
                }
                float hs = 0.f;
                #pragma unroll
                for (int r = 0; r < 4; ++r) {
                    int t = kgrp * 4 + r;
                    float hl = 0.f, c = 0.f;
                    if (t < TL) {
                        float i_ = a0[r] + bi, o_ = a1[r] + bo, u_ = a2[r] + bu;
                        c = fsig(i_) * ftanh(u_) + bf2f(cib[lt * 16 + t][h]);
                        hl = fsig(o_) * ftanh(c);
                    }
                    cl[lt][r] = c;
                    hs += hl;
                    hlb[lt * 16 + t][h] = f2bf_fast(hl);
                }
                hsum[lt] = hs;
            }
        };

        auto forget_pass = [&](int pb) {
            #pragma unroll
            for (int lt = 0; lt < PASS; ++lt) {
                const int tt = pb * PASS + lt;
                f32x4 fa = {0,0,0,0};
                #pragma unroll
                for (int kt = 0; kt < 2; ++kt) {
                    bf16x8 a = *(const bf16x8*)&hlb[lt * 16 + arow][kt * 32 + kgrp * 8];
                    fa = __builtin_amdgcn_mfma_f32_16x16x32_bf16(a, Bf[kt], fa, 0, 0, 0);
                }
                float credsum = 0.f;
                #pragma unroll
                for (int r = 0; r < 4; ++r) {
                    int t = kgrp * 4 + r;
                    if (t < TL) credsum += fsig(fa[r] + fb) * cl[lt][r];
                }
                float hs = hsum[lt];
                hs += __shfl_xor(hs, 16);           hs += __shfl_xor(hs, 32);
                credsum += __shfl_xor(credsum, 16); credsum += __shfl_xor(credsum, 32);
                if (kgrp == 0) {
                    htb[tt][h] = f2bf_fast(hs);
                    credb[tt][h] = credsum;
                }
            }
        };

        issueX(0); issueC(0);
        for (int i = tid; i < 64 * 14; i += 256) {
            int r = i / 14, cu = i - r * 14;
            *(uint_t*)&xsb[r][100 + cu * 2] = 0;
        }
        for (int i = tid; i < PASS * 50; i += 256) {
            int lt = i / 50, cu = i - lt * 50;
            *(uint_t*)&xsb[lt * 16 + 15][cu * 2] = 0;
        }
        for (int i = tid; i < (16 - TPB) * 36; i += 256) {
            int r = i / 36, cu = i - r * 36;
            *(uint_t*)&htb[TPB + r][cu * 2] = 0;
        }
        writeX(); writeC();
        wave_barrier();        // pass1 staged
        issueX(1); issueC(1);  // prefetch pass2
        leaf_pass();
        wave_barrier();        // hlb p1 ready; xsb/cib p1 reads done
        writeX(); writeC();    // stage pass2
        forget_pass(0);
        wave_barrier();        // pass2 staged; hlb p1 reads done
        leaf_pass();
        wave_barrier();        // hlb p2 ready
        forget_pass(1);
        wave_barrier();        // htb/credb complete

        f32x4 r0 = {0,0,0,0}, r1 = {0,0,0,0}, r2 = {0,0,0,0};
        #pragma unroll
        for (int kt = 0; kt < 2; ++kt) {
            bf16x8 a = *(const bf16x8*)&htb[arow][kt * 32 + kgrp * 8];
            bf16x8 b0 = *(const bf16x8*)(Wb_u + (((size_t)kt * 12 + w)     * 64 + lane) * 8);
            bf16x8 b1 = *(const bf16x8*)(Wb_u + (((size_t)kt * 12 + w + 4) * 64 + lane) * 8);
            bf16x8 b2 = *(const bf16x8*)(Wb_u + (((size_t)kt * 12 + w + 8) * 64 + lane) * 8);
            r0 = __builtin_amdgcn_mfma_f32_16x16x32_bf16(a, b0, r0, 0, 0, 0);
            r1 = __builtin_amdgcn_mfma_f32_16x16x32_bf16(a, b1, r1, 0, 0, 0);
            r2 = __builtin_amdgcn_mfma_f32_16x16x32_bf16(a, b2, r2, 0, 0, 0);
        }
        #pragma unroll
        for (int r = 0; r < 4; ++r) {
            int m = kgrp * 4 + r;
            if (m < TPB && base + m < Ntrees) {
                float c = fsig(r0[r] + bi) * ftanh(r2[r] + bu) + credb[m][h];
                h_rootb[(size_t)(base + m) * HD + h] = f2bf_fast(fsig(r1[r] + bo) * ftanh(c));
            }
        }
        return;
    }

    if (other_idx < NB_FILL) {
        // ---------------- fill ----------------
        const int fb = other_idx;
        const int stride = NB_FILL * 256;
        const int4* s4 = (const int4*)edge_src;
        const int4* d4 = (const int4*)edge_dst;
        const int E4 = E >> 2;
        for (int e = fb * 256 + tid; e < E4; e += stride) {
            int4 sv = s4[e];
            int4 dv = d4[e];
            csr_src[atomicAdd(&cursor[dv.x], 1)] = sv.x;
            csr_src[atomicAdd(&cursor[dv.y], 1)] = sv.y;
            csr_src[atomicAdd(&cursor[dv.z], 1)] = sv.z;
            csr_src[atomicAdd(&cursor[dv.w], 1)] = sv.w;
        }
        for (int e = (E & ~3) + fb * 256 + tid; e < E; e += stride) {
            int p = atomicAdd(&cursor[edge_dst[e]], 1);
            csr_src[p] = edge_src[e];
        }
        return;
    }

    // ---------------- elr ----------------
    {
        float* xs = (float*)smem;                 // 6400 floats
        float* Bs = (float*)(smem + 25600);       // 800 floats
        const int blk = other_idx - NB_FILL;
        const int base = blk * 64;
        for (int i = tid; i < 8 * XD; i += 256) Bs[i] = B_lr[i];
        const size_t goff = (size_t)base * XD;
        long lim = (long)N * XD - (long)goff;
        if (lim > 64 * XD) lim = 64 * XD;
        for (int i = tid; i < lim; i += 256) xs[i] = cfg_type[goff + i];
        __syncthreads();
        for (int o = tid; o < 512; o += 256) {
            int r = o >> 3, q = o & 7;
            int node = base + r;
            if (node < N) {
                float s = 0.f;
                #pragma unroll 4
                for (int k = 0; k < XD; ++k)
                    s = fmaf(xs[r * XD + k], Bs[q * XD + k], s);
                ((q < 4) ? el : er)[(size_t)node * NHEADS + (q & 3)] = s;
            }
        }
    }
}

// ---------------- K4: per-dst edge softmax + aggregation + W_out + replicated column exp-sum ----------------
// 8 edge slots x 8 channel-octets per wave (uint4 16B row loads).
__global__ __launch_bounds__(256) void agg_kernel(
    const ushort_t* __restrict__ h_rootb, const float* __restrict__ el,
    const float* __restrict__ er, const int* __restrict__ offs,
    const int* __restrict__ csr_src, const float* __restrict__ W_out_T,
    const float* __restrict__ bias_g, float* __restrict__ rst,
    float* __restrict__ colsum_rep, int N)
{
    const int wid = threadIdx.x >> 6;
    const int lane = threadIdx.x & 63;
    const int n = blockIdx.x * 4 + wid;
    const bool active = (n < N);
    __shared__ __align__(16) float s_agg[4][NHEADS][HD];
    __shared__ float s_ex[4][128];

    int beg = 0, deg = 0;
    float4 erv = make_float4(0.f, 0.f, 0.f, 0.f);
    if (active) {
        beg = offs[n];
        deg = offs[n + 1] - beg;
        erv = *(const float4*)&er[(size_t)n * NHEADS];
    }
    const uint4* hb4 = (const uint4*)h_rootb;
    const int cp8 = lane & 7;     // channel octet (8 bf16 = 16B)
    const int slot = lane >> 3;   // edge slot 0..7

    float acc[NHEADS][8];
    #pragma unroll
    for (int hh = 0; hh < NHEADS; ++hh)
        #pragma unroll
        for (int c = 0; c < 8; ++c) acc[hh][c] = 0.f;
    float ps[NHEADS] = {0.f, 0.f, 0.f, 0.f};

    for (int c0 = 0; c0 < deg; c0 += 64) {
        const int j = c0 + lane;
        int srcv = 0;
        float ez0 = 0.f, ez1 = 0.f, ez2 = 0.f, ez3 = 0.f;
        if (j < deg) {
            srcv = csr_src[beg + j];
            float4 elv = *(const float4*)&el[(size_t)srcv * NHEADS];
            float t0 = elv.x + erv.x, t1 = elv.y + erv.y;
            float t2 = elv.z + erv.z, t3 = elv.w + erv.w;
            t0 = t0 > 0.f ? t0 : 0.2f * t0;
            t1 = t1 > 0.f ? t1 : 0.2f * t1;
            t2 = t2 > 0.f ? t2 : 0.2f * t2;
            t3 = t3 > 0.f ? t3 : 0.2f * t3;
            ez0 = __expf(t0); ez1 = __expf(t1);
            ez2 = __expf(t2); ez3 = __expf(t3);
            ps[0] += ez0; ps[1] += ez1; ps[2] += ez2; ps[3] += ez3;
        }
        const int cnt2 = min(64, deg - c0);
        #pragma unroll 2
        for (int j0 = 0; j0 < cnt2; j0 += 8) {
            const int sidx = j0 + slot;        // slots beyond cnt2 have ez==0 -> contribute 0
            const int sj = __shfl(srcv, sidx);
            const float e0 = __shfl(ez0, sidx);
            const float e1 = __shfl(ez1, sidx);
            const float e2 = __shfl(ez2, sidx);
            const float e3 = __shfl(ez3, sidx);
            const uint4 hv = hb4[(size_t)sj * 8 + cp8];
            float hc[8];
            hc[0] = bf2f((ushort_t)(hv.x & 0xffffu)); hc[1] = bf2f((ushort_t)(hv.x >> 16));
            hc[2] = bf2f((ushort_t)(hv.y & 0xffffu)); hc[3] = bf2f((ushort_t)(hv.y >> 16));
            hc[4] = bf2f((ushort_t)(hv.z & 0xffffu)); hc[5] = bf2f((ushort_t)(hv.z >> 16));
            hc[6] = bf2f((ushort_t)(hv.w & 0xffffu)); hc[7] = bf2f((ushort_t)(hv.w >> 16));
            #pragma unroll
            for (int c = 0; c < 8; ++c) {
                acc[0][c] = fmaf(e0, hc[c], acc[0][c]);
                acc[1][c] = fmaf(e1, hc[c], acc[1][c]);
                acc[2][c] = fmaf(e2, hc[c], acc[2][c]);
                acc[3][c] = fmaf(e3, hc[c], acc[3][c]);
            }
        }
    }

    #pragma unroll
    for (int hh = 0; hh < NHEADS; ++hh)
        for (int off = 1; off < 64; off <<= 1)
            ps[hh] += __shfl_xor(ps[hh], off);
    // reduce the 8 edge slots (same channel octet at lanes l, l+8, ..., l+56)
    #pragma unroll
    for (int hh = 0; hh < NHEADS; ++hh)
        #pragma unroll
        for (int c = 0; c < 8; ++c) {
            acc[hh][c] += __shfl_xor(acc[hh][c], 8);
            acc[hh][c] += __shfl_xor(acc[hh][c], 16);
            acc[hh][c] += __shfl_xor(acc[hh][c], 32);
        }

    if (slot == 0) {
        #pragma unroll
        for (int hh = 0; hh < NHEADS; ++hh) {
            float inv = (deg > 0) ? 1.f / ps[hh] : 0.f;
            float4 v0 = make_float4(acc[hh][0] * inv, acc[hh][1] * inv,
                                    acc[hh][2] * inv, acc[hh][3] * inv);
            float4 v1 = make_float4(acc[hh][4] * inv, acc[hh][5] * inv,
                                    acc[hh][6] * inv, acc[hh][7] * inv);
            *(float4*)&s_agg[wid][hh][8 * cp8]     = v0;
            *(float4*)&s_agg[wid][hh][8 * cp8 + 4] = v1;
        }
    }
    // rst + exp partials (same-wave LDS producer/consumer)
    #pragma unroll
    for (int t = 0; t < 2; ++t) {
        const int idx = t * 64 + lane;
        const int hh = idx >> 5, o = idx & 31;
        float s = bias_g[idx];
        #pragma unroll 8
        for (int c = 0; c < HD; ++c)
            s = fmaf(s_agg[wid][hh][c], W_out_T[c * OUTD + o], s);
        float ex = 0.f;
        if (active) {
            rst[(size_t)n * 128 + idx] = s;
            ex = __expf(s);
        }
        s_ex[wid][idx] = ex;
    }
    __syncthreads();
    if (threadIdx.x < 128) {
        float s = s_ex[0][threadIdx.x] + s_ex[1][threadIdx.x]
                + s_ex[2][threadIdx.x] + s_ex[3][threadIdx.x];
        atomicAdd(&colsum_rep[(blockIdx.x & (NREP - 1)) * 128 + threadIdx.x], s);
    }
}

// ---------------- K5: softmax + folded classifier ----------------
__global__ __launch_bounds__(256) void final_kernel(
    const float* __restrict__ rst, const float* __restrict__ colsum_rep,
    const float* __restrict__ W1, const float* __restrict__ b1,
    const float* __restrict__ W2, const float* __restrict__ b2,
    float* __restrict__ out, int N)
{
    __shared__ float M[2][OUTD];
    __shared__ float bv[2];
    __shared__ float cs[128];
    const int tid = threadIdx.x;
    if (tid < 64) {
        const int r = tid >> 5, o = tid & 31;
        float s = 0.f;
        #pragma unroll
        for (int k = 0; k < 16; ++k) s = fmaf(W2[r * 16 + k], W1[k * 32 + o], s);
        M[r][o] = s;
    }
    if (tid < 2) {
        float s = b2[tid];
        #pragma unroll
        for (int k = 0; k < 16; ++k) s = fmaf(b1[k], W2[tid * 16 + k], s);
        bv[tid] = s;
    }
    if (tid >= 128) {
        const int c = tid - 128;
        float s = 0.f;
        #pragma unroll 8
        for (int rp = 0; rp < NREP; ++rp) s += colsum_rep[rp * 128 + c];
        cs[c] = s;
    }
    __syncthreads();
    for (int row = blockIdx.x * 256 + tid; row < N * 4; row += gridDim.x * 256) {
        const int n = row >> 2, h = row & 3;
        const float* r = rst + (size_t)n * 128 + h * 32;
        float a0 = bv[0], a1 = bv[1];
        #pragma unroll 4
        for (int o = 0; o < OUTD; ++o) {
            const int c = h * 32 + o;
            float p = __expf(r[o]) / cs[c];
            a0 = fmaf(p, M[0][o], a0);
            a1 = fmaf(p, M[1][o], a1);
        }
        out[(size_t)row * 2 + 0] = a0;
        out[(size_t)row * 2 + 1] = a1;
    }
}

extern "C" void kernel_launch(void* const* d_in, const int* in_sizes, int n_in,
                              void* d_out, int out_size, void* d_ws, size_t ws_size,
                              hipStream_t stream) {
    const float* ast_x   = (const float*)d_in[0];
    const float* c_init  = (const float*)d_in[1];
    const float* cfg_type= (const float*)d_in[2];
    const float* W_iou   = (const float*)d_in[3];
    const float* b_iou   = (const float*)d_in[4];
    const float* U_iou   = (const float*)d_in[5];
    const float* U_f_W   = (const float*)d_in[6];
    const float* U_f_b   = (const float*)d_in[7];
    const float* Wt      = (const float*)d_in[8];
    const float* Wfc     = (const float*)d_in[9];
    const float* attn_l  = (const float*)d_in[10];
    const float* attn_r  = (const float*)d_in[11];
    const float* W_out   = (const float*)d_in[12];
    const float* bias_g  = (const float*)d_in[13];
    const float* W1      = (const float*)d_in[14];
    const float* b1      = (const float*)d_in[15];
    const float* W2      = (const float*)d_in[16];
    const float* b2      = (const float*)d_in[17];
    const int* edge_src  = (const int*)d_in[18];
    const int* edge_dst  = (const int*)d_in[19];

    const int N = in_sizes[2] / XD;      // 20000
    const int E = in_sizes[18];          // 640000
    (void)n_in; (void)out_size; (void)ws_size;

    char* w = (char*)d_ws;
    auto take = [&](size_t bytes) { char* p = w; w += (bytes + 255) & ~(size_t)255; return p; };
    ushort_t* h_rootb = (ushort_t*)take((size_t)N * HD * 2);
    float*    el      = (float*)take((size_t)N * NHEADS * 4);
    float*    er      = (float*)take((size_t)N * NHEADS * 4);
    int*      cnt     = (int*)take((size_t)N * 4);
    int*      offs    = (int*)take(((size_t)N + 1) * 4);
    int*      cursor  = (int*)take((size_t)N * 4);
    int*      csr_src = (int*)take((size_t)E * 4);
    float*    rst     = (float*)take((size_t)N * 128 * 4);
    ushort_t* Wb_iou  = (ushort_t*)take(24576 * 2);
    ushort_t* Wb_f    = (ushort_t*)take(4096 * 2);
    ushort_t* Wb_u    = (ushort_t*)take(12288 * 2);
    float*    B_lr    = (float*)take(800 * 4);
    float*    W_out_T = (float*)take((size_t)HD * OUTD * 4);
    float*    colsum_rep = (float*)take((size_t)NREP * 128 * 4);

    const int NB_TREE  = (N + TPB - 1) / TPB;          // 2500
    const int NB_ELR   = (N + 63) / 64;                // 313
    const int NB_TOTAL = NB_TREE + NB_FILL + NB_ELR;   // 3453

    hipMemsetAsync(cnt, 0, (size_t)N * 4, stream);
    setup_count<<<NB_SETUP + NB_COUNT, 256, 0, stream>>>(
        W_iou, U_f_W, U_iou, Wt, Wfc, attn_l, attn_r, W_out,
        Wb_iou, Wb_f, Wb_u, B_lr, W_out_T, colsum_rep, edge_dst, cnt, E);
    scan_kernel<<<1, 1024, 0, stream>>>(cnt, offs, cursor, N);
    mega_kernel<<<NB_TOTAL, 256, 0, stream>>>(
        edge_src, edge_dst, cursor, csr_src, E,
        ast_x, c_init, Wb_iou, Wb_f, Wb_u, b_iou, U_f_b, h_rootb, N, NB_TREE, NB_TOTAL,
        cfg_type, B_lr, el, er, N);
    agg_kernel<<<(N + 3) / 4, 256, 0, stream>>>(
        h_rootb, el, er, offs, csr_src, W_out_T, bias_g, rst, colsum_rep, N);
    final_kernel<<<(N * 4 + 255) / 256, 256, 0, stream>>>(
        rst, colsum_rep, W1, b1, W2, b2, (float*)d_out, N);
}

// Round 15
// 197.516 us; speedup vs baseline: 1.1022x; 1.1022x over previous
//
#include <hip/hip_runtime.h>
#include <hip/hip_bf16.h>
#include <math.h>

#define XD 100
#define HD 64
#define TL 15
#define NHEADS 4
#define OUTD 32
#define TPB 8        // trees per treelstm block
#define PASS 4       // trees per LDS pass
#define NREP 32      // colsum replicas (atomic contention fix)
#define NB_SETUP 161
#define NB_COUNT 640
#define NB_FILL 640

typedef unsigned short ushort_t;
typedef unsigned int uint_t;
typedef __attribute__((ext_vector_type(8))) short bf16x8;
typedef __attribute__((ext_vector_type(4))) float f32x4;
typedef __attribute__((ext_vector_type(4))) unsigned short us4;

__device__ __forceinline__ ushort_t f2bf(float x) {
    __hip_bfloat16 h = __float2bfloat16(x);
    return *reinterpret_cast<ushort_t*>(&h);
}
__device__ __forceinline__ ushort_t f2bf_fast(float x) { // 3-op RNE (finite inputs)
    uint_t b = __float_as_uint(x);
    return (ushort_t)((b + 0x7FFFu + ((b >> 16) & 1u)) >> 16);
}
__device__ __forceinline__ float bf2f(ushort_t u) {
    unsigned int v = ((unsigned int)u) << 16;
    return __uint_as_float(v);
}
__device__ __forceinline__ float fsig(float x) {
    return __builtin_amdgcn_rcpf(1.0f + __expf(-x));
}
__device__ __forceinline__ float ftanh(float x) {
    return 2.0f * __builtin_amdgcn_rcpf(1.0f + __expf(-2.0f * x)) - 1.0f;
}
__device__ __forceinline__ void wave_barrier() {   // LDS handoff only, no vmcnt drain
    asm volatile("s_waitcnt lgkmcnt(0)" ::: "memory");
    __builtin_amdgcn_s_barrier();
}

// ---------------- K1: setup (blocks 0..160) || edge count (blocks 161..) ----------------
__global__ __launch_bounds__(256) void setup_count(
    const float* __restrict__ W_iou, const float* __restrict__ U_f_W,
    const float* __restrict__ U_iou, const float* __restrict__ Wt,
    const float* __restrict__ Wfc, const float* __restrict__ attn_l,
    const float* __restrict__ attn_r, const float* __restrict__ W_out,
    ushort_t* __restrict__ Wb_iou, ushort_t* __restrict__ Wb_f,
    ushort_t* __restrict__ Wb_u, float* __restrict__ B_lr,
    float* __restrict__ W_out_T, float* __restrict__ colsum_rep,
    const int* __restrict__ edge_dst, int* __restrict__ cnt, int E)
{
    __shared__ float A_s[8][HD];
    const int blk = blockIdx.x;
    const int tid = threadIdx.x;
    if (blk < 160) {
        int idx = blk * 256 + tid;               // [0, 40960)
        if (idx < 24576) {                       // W_iou: 4kt x 12nt
            int j = idx & 7, l = (idx >> 3) & 63, f = idx >> 9;
            int kt = f / 12, nt = f % 12;
            int k = kt * 32 + ((l >> 4) * 8) + j;
            int nn = nt * 16 + (l & 15);
            float v = (k < XD) ? W_iou[nn * XD + k] : 0.f;
            Wb_iou[idx] = f2bf(v);
        } else if (idx < 24576 + 4096) {         // U_f_W: 2kt x 4nt
            int t = idx - 24576;
            int j = t & 7, l = (t >> 3) & 63, f = t >> 9;
            int kt = f >> 2, nt = f & 3;
            int k = kt * 32 + ((l >> 4) * 8) + j;
            int nn = nt * 16 + (l & 15);
            Wb_f[t] = f2bf(U_f_W[nn * HD + k]);
        } else {                                  // U_iou: 2kt x 12nt
            int t = idx - 24576 - 4096;
            int j = t & 7, l = (t >> 3) & 63, f = t >> 9;
            int kt = f / 12, nt = f % 12;
            int k = kt * 32 + ((l >> 4) * 8) + j;
            int g = nt * 16 + (l & 15);
            Wb_u[t] = f2bf(U_iou[g * HD + k]);
        }
    } else if (blk == 160) {
        for (int o = tid; o < 8 * HD; o += 256) {
            int q = o >> 6, c = o & 63;
            int h = q & 3;
            const float* attn = (q < 4) ? attn_l : attn_r;
            float s = 0.f;
            #pragma unroll 4
            for (int oo = 0; oo < OUTD; ++oo)
                s = fmaf(attn[h * OUTD + oo], Wfc[(h * OUTD + oo) * HD + c], s);
            A_s[q][c] = s;
        }
        // zero colsum replicas (consumed by agg, launched 2 kernels later)
        for (int i = tid; i < NREP * 128; i += 256) colsum_rep[i] = 0.f;
        __syncthreads();
        for (int o = tid; o < 8 * XD; o += 256) {
            int q = o / XD, x = o - q * XD;
            float s = 0.f;
            #pragma unroll 4
            for (int c = 0; c < HD; ++c)
                s = fmaf(A_s[q][c], Wt[c * XD + x], s);
            B_lr[o] = s;
        }
        for (int idx = tid; idx < HD * OUTD; idx += 256) {
            int c = idx >> 5, o = idx & 31;
            W_out_T[idx] = W_out[o * HD + c];
        }
    } else {
        const int cb = blk - NB_SETUP;
        const int stride = NB_COUNT * 256;
        const int4* d4 = (const int4*)edge_dst;
        const int E4 = E >> 2;
        for (int e = cb * 256 + tid; e < E4; e += stride) {
            int4 v = d4[e];
            atomicAdd(&cnt[v.x], 1); atomicAdd(&cnt[v.y], 1);
            atomicAdd(&cnt[v.z], 1); atomicAdd(&cnt[v.w], 1);
        }
        for (int e = (E & ~3) + cb * 256 + tid; e < E; e += stride)
            atomicAdd(&cnt[edge_dst[e]], 1);
    }
}

// ---------------- K2: scan ----------------
__global__ __launch_bounds__(1024) void scan_kernel(
    const int* __restrict__ cnt, int* __restrict__ offs, int* __restrict__ cursor, int N)
{
    __shared__ int part[1024];
    const int tid = threadIdx.x;
    const int per = (N + 1023) >> 10;
    int begin = tid * per;
    int end = begin + per; if (end > N) end = N;
    int s = 0;
    for (int i = begin; i < end && i < N; ++i) s += cnt[i];
    part[tid] = s;
    __syncthreads();
    for (int off = 1; off < 1024; off <<= 1) {
        int t = (tid >= off) ? part[tid - off] : 0;
        __syncthreads();
        part[tid] += t;
        __syncthreads();
    }
    int run = part[tid] - s;
    for (int i = begin; i < end && i < N; ++i) {
        offs[i] = run; cursor[i] = run; run += cnt[i];
    }
    if (tid == 1023) offs[N] = part[1023];
}

// ---------------- K3: mega = treelstm || fill || elr, STRIPED (31.1 KB LDS) ----------------
__global__ __launch_bounds__(256) void mega_kernel(
    // fill
    const int* __restrict__ edge_src, const int* __restrict__ edge_dst,
    int* __restrict__ cursor, int* __restrict__ csr_src, int E,
    // treelstm
    const float* __restrict__ ast_x, const float* __restrict__ c_init,
    const ushort_t* __restrict__ Wb_iou, const ushort_t* __restrict__ Wb_f,
    const ushort_t* __restrict__ Wb_u, const float* __restrict__ b_iou,
    const float* __restrict__ U_f_b, ushort_t* __restrict__ h_rootb,
    int Ntrees, int NB_TREE, int NB_TOTAL,
    // elr
    const float* __restrict__ cfg_type, const float* __restrict__ B_lr,
    float* __restrict__ el, float* __restrict__ er, int N)
{
    __shared__ __align__(16) char smem[31104];
    const int tid = threadIdx.x;

    // Bresenham stripe: tree blocks interleaved with fill/elr so they co-run.
    const long long b = blockIdx.x;
    const int fb0 = (int)((b * NB_TREE) / NB_TOTAL);
    const int fb1 = (int)(((b + 1) * NB_TREE) / NB_TOTAL);
    const bool is_tree = (fb1 > fb0);
    const int tree_idx = fb0;
    const int other_idx = (int)(b - fb0);

    if (is_tree) {
        ushort_t (*xsb)[136] = (ushort_t(*)[136])smem;                    // 17408 B
        ushort_t (*hlb)[72]  = (ushort_t(*)[72])(smem + 17408);           //  9216 B
        ushort_t (*htb)[72]  = (ushort_t(*)[72])(smem + 26624);           //  2304 B
        float    (*credb)[68]= (float(*)[68])(smem + 28928);              //  2176 B

        const int lane = tid & 63;
        const int w = tid >> 6;
        const int arow = lane & 15;
        const int kgrp = lane >> 4;
        const int h = w * 16 + arow;
        const int base = tree_idx * TPB;

        const float bi = b_iou[h], bo = b_iou[64 + h], bu = b_iou[128 + h];
        const float fb = U_f_b[h];

        bf16x8 Bl[12];
        #pragma unroll
        for (int kt = 0; kt < 4; ++kt)
            #pragma unroll
            for (int j = 0; j < 3; ++j)
                Bl[kt * 3 + j] = *(const bf16x8*)(Wb_iou + (((size_t)kt * 12 + (w + 4 * j)) * 64 + lane) * 8);
        bf16x8 Bf[2];
        #pragma unroll
        for (int kt = 0; kt < 2; ++kt)
            Bf[kt] = *(const bf16x8*)(Wb_f + (((size_t)kt * 4 + w) * 64 + lane) * 8);

        const float4* xb4 = (const float4*)ast_x;
        float4 xv[6];

        auto issueX = [&](int pb) {
            #pragma unroll
            for (int k = 0; k < 6; ++k) {
                int i4 = tid + k * 256;
                int idx = i4 < 1500 ? i4 : 1499;
                int tt = pb * PASS + idx / 375, rem = idx % 375;
                int n = base + tt; if (n >= Ntrees) n = Ntrees - 1;
                xv[k] = xb4[(size_t)n * 400 + 25 + rem];
            }
        };
        auto writeX = [&]() {
            #pragma unroll
            for (int k = 0; k < 6; ++k) {
                int i4 = tid + k * 256;
                if (i4 < 1500) {
                    int lt = i4 / 375, rem = i4 - lt * 375;
                    int row = rem / 25, c4 = rem - row * 25;
                    us4 p;
                    p[0] = f2bf_fast(xv[k].x); p[1] = f2bf_fast(xv[k].y);
                    p[2] = f2bf_fast(xv[k].z); p[3] = f2bf_fast(xv[k].w);
                    *(us4*)&xsb[lt * 16 + row][c4 * 4] = p;
                }
            }
        };

        float cl[PASS][4];
        float hsum[PASS];

        auto leaf_pass = [&](int pb) {
            #pragma unroll
            for (int lt = 0; lt < PASS; ++lt) {
                int n = base + pb * PASS + lt; if (n >= Ntrees) n = Ntrees - 1;
                const float* cbp = c_init + ((size_t)n * 16 + 1) * HD;
                float cb[4];
                #pragma unroll
                for (int r = 0; r < 4; ++r) {
                    int t = kgrp * 4 + r;
                    cb[r] = (t < TL) ? cbp[t * HD + h] : 0.f;
                }
                f32x4 a0 = {0,0,0,0}, a1 = {0,0,0,0}, a2 = {0,0,0,0};
                #pragma unroll
                for (int kt = 0; kt < 4; ++kt) {
                    bf16x8 a = *(const bf16x8*)&xsb[lt * 16 + arow][kt * 32 + kgrp * 8];
                    a0 = __builtin_amdgcn_mfma_f32_16x16x32_bf16(a, Bl[kt * 3 + 0], a0, 0, 0, 0);
                    a1 = __builtin_amdgcn_mfma_f32_16x16x32_bf16(a, Bl[kt * 3 + 1], a1, 0, 0, 0);
                    a2 = __builtin_amdgcn_mfma_f32_16x16x32_bf16(a, Bl[kt * 3 + 2], a2, 0, 0, 0);
                }
                float hs = 0.f;
                #pragma unroll
                for (int r = 0; r < 4; ++r) {
                    int t = kgrp * 4 + r;
                    float hl = 0.f, c = 0.f;
                    if (t < TL) {
                        float i_ = a0[r] + bi, o_ = a1[r] + bo, u_ = a2[r] + bu;
                        c = fsig(i_) * ftanh(u_) + cb[r];
                        hl = fsig(o_) * ftanh(c);
                    }
                    cl[lt][r] = c;
                    hs += hl;
                    hlb[lt * 16 + t][h] = f2bf_fast(hl);
                }
                hsum[lt] = hs;
            }
        };

        auto forget_pass = [&](int pb) {
            #pragma unroll
            for (int lt = 0; lt < PASS; ++lt) {
                const int tt = pb * PASS + lt;
                f32x4 fa = {0,0,0,0};
                #pragma unroll
                for (int kt = 0; kt < 2; ++kt) {
                    bf16x8 a = *(const bf16x8*)&hlb[lt * 16 + arow][kt * 32 + kgrp * 8];
                    fa = __builtin_amdgcn_mfma_f32_16x16x32_bf16(a, Bf[kt], fa, 0, 0, 0);
                }
                float credsum = 0.f;
                #pragma unroll
                for (int r = 0; r < 4; ++r) {
                    int t = kgrp * 4 + r;
                    if (t < TL) credsum += fsig(fa[r] + fb) * cl[lt][r];
                }
                float hs = hsum[lt];
                hs += __shfl_xor(hs, 16);           hs += __shfl_xor(hs, 32);
                credsum += __shfl_xor(credsum, 16); credsum += __shfl_xor(credsum, 32);
                if (kgrp == 0) {
                    htb[tt][h] = f2bf_fast(hs);
                    credb[tt][h] = credsum;
                }
            }
        };

        issueX(0);
        for (int i = tid; i < 64 * 14; i += 256) {
            int r = i / 14, cu = i - r * 14;
            *(uint_t*)&xsb[r][100 + cu * 2] = 0;
        }
        for (int i = tid; i < PASS * 50; i += 256) {
            int lt = i / 50, cu = i - lt * 50;
            *(uint_t*)&xsb[lt * 16 + 15][cu * 2] = 0;
        }
        for (int i = tid; i < (16 - TPB) * 36; i += 256) {
            int r = i / 36, cu = i - r * 36;
            *(uint_t*)&htb[TPB + r][cu * 2] = 0;
        }
        writeX();
        wave_barrier();        // pass1 staged
        issueX(1);             // prefetch pass2
        leaf_pass(0);
        wave_barrier();        // hlb p1 ready; xsb p1 reads done
        writeX();              // stage pass2
        forget_pass(0);
        wave_barrier();        // pass2 staged; hlb p1 reads done
        leaf_pass(1);
        wave_barrier();        // hlb p2 ready
        forget_pass(1);
        wave_barrier();        // htb/credb complete

        f32x4 r0 = {0,0,0,0}, r1 = {0,0,0,0}, r2 = {0,0,0,0};
        #pragma unroll
        for (int kt = 0; kt < 2; ++kt) {
            bf16x8 a = *(const bf16x8*)&htb[arow][kt * 32 + kgrp * 8];
            bf16x8 b0 = *(const bf16x8*)(Wb_u + (((size_t)kt * 12 + w)     * 64 + lane) * 8);
            bf16x8 b1 = *(const bf16x8*)(Wb_u + (((size_t)kt * 12 + w + 4) * 64 + lane) * 8);
            bf16x8 b2 = *(const bf16x8*)(Wb_u + (((size_t)kt * 12 + w + 8) * 64 + lane) * 8);
            r0 = __builtin_amdgcn_mfma_f32_16x16x32_bf16(a, b0, r0, 0, 0, 0);
            r1 = __builtin_amdgcn_mfma_f32_16x16x32_bf16(a, b1, r1, 0, 0, 0);
            r2 = __builtin_amdgcn_mfma_f32_16x16x32_bf16(a, b2, r2, 0, 0, 0);
        }
        #pragma unroll
        for (int r = 0; r < 4; ++r) {
            int m = kgrp * 4 + r;
            if (m < TPB && base + m < Ntrees) {
                float c = fsig(r0[r] + bi) * ftanh(r2[r] + bu) + credb[m][h];
                h_rootb[(size_t)(base + m) * HD + h] = f2bf_fast(fsig(r1[r] + bo) * ftanh(c));
            }
        }
        return;
    }

    if (other_idx < NB_FILL) {
        // ---------------- fill ----------------
        const int fb = other_idx;
        const int stride = NB_FILL * 256;
        const int4* s4 = (const int4*)edge_src;
        const int4* d4 = (const int4*)edge_dst;
        const int E4 = E >> 2;
        for (int e = fb * 256 + tid; e < E4; e += stride) {
            int4 sv = s4[e];
            int4 dv = d4[e];
            csr_src[atomicAdd(&cursor[dv.x], 1)] = sv.x;
            csr_src[atomicAdd(&cursor[dv.y], 1)] = sv.y;
            csr_src[atomicAdd(&cursor[dv.z], 1)] = sv.z;
            csr_src[atomicAdd(&cursor[dv.w], 1)] = sv.w;
        }
        for (int e = (E & ~3) + fb * 256 + tid; e < E; e += stride) {
            int p = atomicAdd(&cursor[edge_dst[e]], 1);
            csr_src[p] = edge_src[e];
        }
        return;
    }

    // ---------------- elr ----------------
    {
        float* xs = (float*)smem;                 // 6400 floats (25600 B)
        float* Bs = (float*)(smem + 25600);       // 800 floats (3200 B)
        const int blk = other_idx - NB_FILL;
        const int base = blk * 64;
        for (int i = tid; i < 8 * XD; i += 256) Bs[i] = B_lr[i];
        const size_t goff = (size_t)base * XD;
        long lim = (long)N * XD - (long)goff;
        if (lim > 64 * XD) lim = 64 * XD;
        for (int i = tid; i < lim; i += 256) xs[i] = cfg_type[goff + i];
        __syncthreads();
        for (int o = tid; o < 512; o += 256) {
            int r = o >> 3, q = o & 7;
            int node = base + r;
            if (node < N) {
                float s = 0.f;
                #pragma unroll 4
                for (int k = 0; k < XD; ++k)
                    s = fmaf(xs[r * XD + k], Bs[q * XD + k], s);
                ((q < 4) ? el : er)[(size_t)node * NHEADS + (q & 3)] = s;
            }
        }
    }
}

// ---------------- K4: per-dst edge softmax + aggregation + W_out + replicated column exp-sum ----------------
// 4 edge slots x 16 channel-quads per wave (R13 measured-best shape).
__global__ __launch_bounds__(256) void agg_kernel(
    const ushort_t* __restrict__ h_rootb, const float* __restrict__ el,
    const float* __restrict__ er, const int* __restrict__ offs,
    const int* __restrict__ csr_src, const float* __restrict__ W_out_T,
    const float* __restrict__ bias_g, float* __restrict__ rst,
    float* __restrict__ colsum_rep, int N)
{
    const int wid = threadIdx.x >> 6;
    const int lane = threadIdx.x & 63;
    const int n = blockIdx.x * 4 + wid;
    const bool active = (n < N);
    __shared__ __align__(16) float s_agg[4][NHEADS][HD];
    __shared__ float s_ex[4][128];

    int beg = 0, deg = 0;
    float4 erv = make_float4(0.f, 0.f, 0.f, 0.f);
    if (active) {
        beg = offs[n];
        deg = offs[n + 1] - beg;
        erv = *(const float4*)&er[(size_t)n * NHEADS];
    }
    const uint_t* hb = (const uint_t*)h_rootb;
    const int cp4 = lane & 15;    // channel quad (4 bf16 = 8B)
    const int slot = lane >> 4;   // edge slot 0..3

    float4 acc[NHEADS] = {{0,0,0,0},{0,0,0,0},{0,0,0,0},{0,0,0,0}};
    float ps[NHEADS] = {0.f, 0.f, 0.f, 0.f};

    for (int c0 = 0; c0 < deg; c0 += 64) {
        const int j = c0 + lane;
        int srcv = 0;
        float ez0 = 0.f, ez1 = 0.f, ez2 = 0.f, ez3 = 0.f;
        if (j < deg) {
            srcv = csr_src[beg + j];
            float4 elv = *(const float4*)&el[(size_t)srcv * NHEADS];
            float t0 = elv.x + erv.x, t1 = elv.y + erv.y;
            float t2 = elv.z + erv.z, t3 = elv.w + erv.w;
            t0 = t0 > 0.f ? t0 : 0.2f * t0;
            t1 = t1 > 0.f ? t1 : 0.2f * t1;
            t2 = t2 > 0.f ? t2 : 0.2f * t2;
            t3 = t3 > 0.f ? t3 : 0.2f * t3;
            ez0 = __expf(t0); ez1 = __expf(t1);
            ez2 = __expf(t2); ez3 = __expf(t3);
            ps[0] += ez0; ps[1] += ez1; ps[2] += ez2; ps[3] += ez3;
        }
        const int cnt2 = min(64, deg - c0);
        #pragma unroll 4
        for (int j0 = 0; j0 < cnt2; j0 += 4) {
            const int sidx = j0 + slot;        // slots beyond cnt2 have ez==0 -> contribute 0
            const int sj = __shfl(srcv, sidx);
            const float e0 = __shfl(ez0, sidx);
            const float e1 = __shfl(ez1, sidx);
            const float e2 = __shfl(ez2, sidx);
            const float e3 = __shfl(ez3, sidx);
            const uint2 hv = ((const uint2*)hb)[(size_t)sj * 16 + cp4];
            const float h0 = bf2f((ushort_t)(hv.x & 0xffffu));
            const float h1 = bf2f((ushort_t)(hv.x >> 16));
            const float h2 = bf2f((ushort_t)(hv.y & 0xffffu));
            const float h3 = bf2f((ushort_t)(hv.y >> 16));
            acc[0].x = fmaf(e0, h0, acc[0].x); acc[0].y = fmaf(e0, h1, acc[0].y);
            acc[0].z = fmaf(e0, h2, acc[0].z); acc[0].w = fmaf(e0, h3, acc[0].w);
            acc[1].x = fmaf(e1, h0, acc[1].x); acc[1].y = fmaf(e1, h1, acc[1].y);
            acc[1].z = fmaf(e1, h2, acc[1].z); acc[1].w = fmaf(e1, h3, acc[1].w);
            acc[2].x = fmaf(e2, h0, acc[2].x); acc[2].y = fmaf(e2, h1, acc[2].y);
            acc[2].z = fmaf(e2, h2, acc[2].z); acc[2].w = fmaf(e2, h3, acc[2].w);
            acc[3].x = fmaf(e3, h0, acc[3].x); acc[3].y = fmaf(e3, h1, acc[3].y);
            acc[3].z = fmaf(e3, h2, acc[3].z); acc[3].w = fmaf(e3, h3, acc[3].w);
        }
    }

    #pragma unroll
    for (int hh = 0; hh < NHEADS; ++hh)
        for (int off = 1; off < 64; off <<= 1)
            ps[hh] += __shfl_xor(ps[hh], off);
    // reduce the 4 edge slots (same channel quad at lanes l, l+16, l+32, l+48)
    #pragma unroll
    for (int hh = 0; hh < NHEADS; ++hh) {
        acc[hh].x += __shfl_xor(acc[hh].x, 16); acc[hh].y += __shfl_xor(acc[hh].y, 16);
        acc[hh].z += __shfl_xor(acc[hh].z, 16); acc[hh].w += __shfl_xor(acc[hh].w, 16);
        acc[hh].x += __shfl_xor(acc[hh].x, 32); acc[hh].y += __shfl_xor(acc[hh].y, 32);
        acc[hh].z += __shfl_xor(acc[hh].z, 32); acc[hh].w += __shfl_xor(acc[hh].w, 32);
    }

    if (slot == 0) {
        #pragma unroll
        for (int hh = 0; hh < NHEADS; ++hh) {
            float inv = (deg > 0) ? 1.f / ps[hh] : 0.f;
            float4 v = make_float4(acc[hh].x * inv, acc[hh].y * inv,
                                   acc[hh].z * inv, acc[hh].w * inv);
            *(float4*)&s_agg[wid][hh][4 * cp4] = v;
        }
    }
    // rst + exp partials (same-wave LDS producer/consumer)
    #pragma unroll
    for (int t = 0; t < 2; ++t) {
        const int idx = t * 64 + lane;
        const int hh = idx >> 5, o = idx & 31;
        float s = bias_g[idx];
        #pragma unroll 8
        for (int c = 0; c < HD; ++c)
            s = fmaf(s_agg[wid][hh][c], W_out_T[c * OUTD + o], s);
        float ex = 0.f;
        if (active) {
            rst[(size_t)n * 128 + idx] = s;
            ex = __expf(s);
        }
        s_ex[wid][idx] = ex;
    }
    __syncthreads();
    if (threadIdx.x < 128) {
        float s = s_ex[0][threadIdx.x] + s_ex[1][threadIdx.x]
                + s_ex[2][threadIdx.x] + s_ex[3][threadIdx.x];
        atomicAdd(&colsum_rep[(blockIdx.x & (NREP - 1)) * 128 + threadIdx.x], s);
    }
}

// ---------------- K5: softmax + folded classifier ----------------
__global__ __launch_bounds__(256) void final_kernel(
    const float* __restrict__ rst, const float* __restrict__ colsum_rep,
    const float* __restrict__ W1, const float* __restrict__ b1,
    const float* __restrict__ W2, const float* __restrict__ b2,
    float* __restrict__ out, int N)
{
    __shared__ float M[2][OUTD];
    __shared__ float bv[2];
    __shared__ float cs[128];
    const int tid = threadIdx.x;
    if (tid < 64) {
        const int r = tid >> 5, o = tid & 31;
        float s = 0.f;
        #pragma unroll
        for (int k = 0; k < 16; ++k) s = fmaf(W2[r * 16 + k], W1[k * 32 + o], s);
        M[r][o] = s;
    }
    if (tid < 2) {
        float s = b2[tid];
        #pragma unroll
        for (int k = 0; k < 16; ++k) s = fmaf(b1[k], W2[tid * 16 + k], s);
        bv[tid] = s;
    }
    if (tid >= 128) {
        const int c = tid - 128;
        float s = 0.f;
        #pragma unroll 8
        for (int rp = 0; rp < NREP; ++rp) s += colsum_rep[rp * 128 + c];
        cs[c] = s;
    }
    __syncthreads();
    for (int row = blockIdx.x * 256 + tid; row < N * 4; row += gridDim.x * 256) {
        const int n = row >> 2, h = row & 3;
        const float* r = rst + (size_t)n * 128 + h * 32;
        float a0 = bv[0], a1 = bv[1];
        #pragma unroll 4
        for (int o = 0; o < OUTD; ++o) {
            const int c = h * 32 + o;
            float p = __expf(r[o]) / cs[c];
            a0 = fmaf(p, M[0][o], a0);
            a1 = fmaf(p, M[1][o], a1);
        }
        out[(size_t)row * 2 + 0] = a0;
        out[(size_t)row * 2 + 1] = a1;
    }
}

extern "C" void kernel_launch(void* const* d_in, const int* in_sizes, int n_in,
                              void* d_out, int out_size, void* d_ws, size_t ws_size,
                              hipStream_t stream) {
    const float* ast_x   = (const float*)d_in[0];
    const float* c_init  = (const float*)d_in[1];
    const float* cfg_type= (const float*)d_in[2];
    const float* W_iou   = (const float*)d_in[3];
    const float* b_iou   = (const float*)d_in[4];
    const float* U_iou   = (const float*)d_in[5];
    const float* U_f_W   = (const float*)d_in[6];
    const float* U_f_b   = (const float*)d_in[7];
    const float* Wt      = (const float*)d_in[8];
    const float* Wfc     = (const float*)d_in[9];
    const float* attn_l  = (const float*)d_in[10];
    const float* attn_r  = (const float*)d_in[11];
    const float* W_out   = (const float*)d_in[12];
    const float* bias_g  = (const float*)d_in[13];
    const float* W1      = (const float*)d_in[14];
    const float* b1      = (const float*)d_in[15];
    const float* W2      = (const float*)d_in[16];
    const float* b2      = (const float*)d_in[17];
    const int* edge_src  = (const int*)d_in[18];
    const int* edge_dst  = (const int*)d_in[19];

    const int N = in_sizes[2] / XD;      // 20000
    const int E = in_sizes[18];          // 640000
    (void)n_in; (void)out_size; (void)ws_size;

    char* w = (char*)d_ws;
    auto take = [&](size_t bytes) { char* p = w; w += (bytes + 255) & ~(size_t)255; return p; };
    ushort_t* h_rootb = (ushort_t*)take((size_t)N * HD * 2);
    float*    el      = (float*)take((size_t)N * NHEADS * 4);
    float*    er      = (float*)take((size_t)N * NHEADS * 4);
    int*      cnt     = (int*)take((size_t)N * 4);
    int*      offs    = (int*)take(((size_t)N + 1) * 4);
    int*      cursor  = (int*)take((size_t)N * 4);
    int*      csr_src = (int*)take((size_t)E * 4);
    float*    rst     = (float*)take((size_t)N * 128 * 4);
    ushort_t* Wb_iou  = (ushort_t*)take(24576 * 2);
    ushort_t* Wb_f    = (ushort_t*)take(4096 * 2);
    ushort_t* Wb_u    = (ushort_t*)take(12288 * 2);
    float*    B_lr    = (float*)take(800 * 4);
    float*    W_out_T = (float*)take((size_t)HD * OUTD * 4);
    float*    colsum_rep = (float*)take((size_t)NREP * 128 * 4);

    const int NB_TREE  = (N + TPB - 1) / TPB;          // 2500
    const int NB_ELR   = (N + 63) / 64;                // 313
    const int NB_TOTAL = NB_TREE + NB_FILL + NB_ELR;   // 3453

    hipMemsetAsync(cnt, 0, (size_t)N * 4, stream);
    setup_count<<<NB_SETUP + NB_COUNT, 256, 0, stream>>>(
        W_iou, U_f_W, U_iou, Wt, Wfc, attn_l, attn_r, W_out,
        Wb_iou, Wb_f, Wb_u, B_lr, W_out_T, colsum_rep, edge_dst, cnt, E);
    scan_kernel<<<1, 1024, 0, stream>>>(cnt, offs, cursor, N);
    mega_kernel<<<NB_TOTAL, 256, 0, stream>>>(
        edge_src, edge_dst, cursor, csr_src, E,
        ast_x, c_init, Wb_iou, Wb_f, Wb_u, b_iou, U_f_b, h_rootb, N, NB_TREE, NB_TOTAL,
        cfg_type, B_lr, el, er, N);
    agg_kernel<<<(N + 3) / 4, 256, 0, stream>>>(
        h_rootb, el, er, offs, csr_src, W_out_T, bias_g, rst, colsum_rep, N);
    final_kernel<<<(N * 4 + 255) / 256, 256, 0, stream>>>(
        rst, colsum_rep, W1, b1, W2, b2, (float*)d_out, N);
}